// Round 24
// baseline (132.133 us; speedup 1.0000x reference)
//
#include <hip/hip_runtime.h>
#include <hip/hip_cooperative_groups.h>
#include <stdint.h>

// ============================================================================
// LaneGraphConvLayerShared: NNConv(edge-conditioned) + root + residual + LN
//
// msg[e,f] = (A_e @ W2)[f], A_e[k*64+d]=a[e,k]*x[src,d]; slot16: a=1, b_edge
//
// R23 (73.5us) = k1(prep+base) -> edge -> ln. Edge is at its falsified
//   latency wall (occupancy register-capped; spill cliff on restructure;
//   pipelining beats traffic cuts). Remaining slack: serial-chain gaps.
// R24: fuse edge+ln via COOPERATIVE launch: edge runs at exactly 2 blocks/CU
//   (VGPR 124, LDS 49664x2 < 160KB) -> G<=512 co-resident -> grid.sync()
//   then grid-strided LN phase in the same kernel. Removes one launch + gap;
//   grid.sync fences the device-scope atomics before LN (G16). G clamped by
//   hipOccupancyMaxActiveBlocksPerMultiprocessor (capture-safe query).
// ============================================================================

namespace cg = cooperative_groups;

typedef _Float16 half8 __attribute__((ext_vector_type(8)));
typedef float floatx4 __attribute__((ext_vector_type(4)));

union HFrag { half8 h8; uint32_t u[4]; uint4 u4; };

__device__ __forceinline__ uint32_t pk_f16(float lo, float hi) {
  auto h = __builtin_amdgcn_cvt_pkrtz(lo, hi);   // __fp16 ext_vector(2)
  union { decltype(h) h2; uint32_t u; } cv;
  cv.h2 = h;
  return cv.u;
}

__device__ __forceinline__ uint32_t pk_mul_f16(uint32_t a, uint32_t b) {
  uint32_t r;
  asm("v_pk_mul_f16 %0, %1, %2" : "=v"(r) : "v"(a), "v"(b));
  return r;
}

__device__ __forceinline__ uint32_t cvt_pk_bf16(float lo, float hi) {
  uint32_t r;
  asm("v_cvt_pk_bf16_f32 %0, %1, %2" : "=v"(r) : "v"(lo), "v"(hi));
  return r;
}

__device__ __forceinline__ uint16_t f32_to_bf16_bits(float x) {
  uint32_t u = __float_as_uint(x);
  u += 0x7fffu + ((u >> 16) & 1u);
  return (uint16_t)(u >> 16);
}

// ws layout:
//   [0,       139264): W2frag  f16 [slot17][kstep2][c4][lane64][i8]
//   [148480, +N*128 ): x_f16 packed pairs [N][32 u32]  (if ws_size permits)
#define W2FRAG_OFF 0
#define XBF_OFF    148480
#define PREP_ELEMS 69632
#define PREP_BLOCKS 272  // ceil(69632/256)

// k1: blocks [0,PREP_BLOCKS) build w2frag (f16 B-frags incl bias slot);
//     blocks [PREP_BLOCKS, +nBase) do base GEMM + emit packed-f16 x.
__global__ __launch_bounds__(256) void k1_kernel(
    const float* __restrict__ x,
    const float* __restrict__ W_edge, const float* __restrict__ b_edge,
    const float* __restrict__ W_root, const float* __restrict__ bias,
    const float* __restrict__ W_res,  const float* __restrict__ b_res,
    uint16_t* __restrict__ w2frag, float* __restrict__ out,
    uint32_t* __restrict__ xpk, int N) {
  int tid = threadIdx.x;
  if (blockIdx.x < PREP_BLOCKS) {
    int gid = blockIdx.x * 256 + tid;
    if (gid < PREP_ELEMS) {
      int i = gid & 7, l = (gid >> 3) & 63, c = (gid >> 9) & 3;
      int t = (gid >> 11) & 1, s = gid >> 12;
      int d = t * 32 + 8 * (l >> 4) + i;
      int f = c * 16 + (l & 15);
      float v = (s < 16) ? W_edge[s * 4096 + d * 64 + f] : b_edge[d * 64 + f];
      w2frag[gid] = (uint16_t)(pk_f16(v, 0.f) & 0xffffu);   // f16 bits
    }
    return;
  }
  typedef short short8 __attribute__((ext_vector_type(8)));
  union AFrag { short8 s8; uint32_t u[4]; };
  int bb = blockIdx.x - PREP_BLOCKS;
  int w = tid >> 6, l = tid & 63;
  int l16 = l & 15, lq = l >> 4;
  union BF { short8 s8; uint16_t h[8]; } Bf[2][4];
#pragma unroll
  for (int t = 0; t < 2; ++t)
#pragma unroll
    for (int c = 0; c < 4; ++c)
#pragma unroll
      for (int i = 0; i < 8; ++i) {
        int d = t * 32 + 8 * lq + i;
        int f = c * 16 + l16;
        Bf[t][c].h[i] = f32_to_bf16_bits(W_root[d * 64 + f] + W_res[d * 64 + f]);
      }
  int arow = bb * 64 + w * 16 + l16;
  float xv[16];
#pragma unroll
  for (int t = 0; t < 2; ++t)
#pragma unroll
    for (int i = 0; i < 8; ++i)
      xv[t * 8 + i] = (arow < N) ? x[arow * 64 + t * 32 + 8 * lq + i] : 0.0f;
  if (xpk != nullptr && arow < N) {
#pragma unroll
    for (int t = 0; t < 2; ++t) {
      uint4 c;
      c.x = pk_f16(xv[t * 8 + 0], xv[t * 8 + 1]);
      c.y = pk_f16(xv[t * 8 + 2], xv[t * 8 + 3]);
      c.z = pk_f16(xv[t * 8 + 4], xv[t * 8 + 5]);
      c.w = pk_f16(xv[t * 8 + 6], xv[t * 8 + 7]);
      *(uint4*)(xpk + arow * 32 + t * 16 + lq * 4) = c;
    }
  }
  AFrag A[2];
#pragma unroll
  for (int t = 0; t < 2; ++t)
#pragma unroll
    for (int j = 0; j < 4; ++j)
      A[t].u[j] = cvt_pk_bf16(xv[t * 8 + 2 * j], xv[t * 8 + 2 * j + 1]);
  floatx4 acc[4];
#pragma unroll
  for (int c = 0; c < 4; ++c) acc[c] = (floatx4){0.f, 0.f, 0.f, 0.f};
#pragma unroll
  for (int t = 0; t < 2; ++t)
#pragma unroll
    for (int c = 0; c < 4; ++c)
      acc[c] = __builtin_amdgcn_mfma_f32_16x16x32_bf16(A[t].s8, Bf[t][c].s8, acc[c], 0, 0, 0);
#pragma unroll
  for (int c = 0; c < 4; ++c) {
    int f = c * 16 + l16;
    float bs = bias[f] + b_res[f];
#pragma unroll
    for (int r = 0; r < 4; ++r) {
      int row = bb * 64 + w * 16 + lq * 4 + r;
      if (row < N) out[row * 64 + f] = acc[c][r] + bs;
    }
  }
}

// edge+ln fused (cooperative): R23 edge body, grid.sync, grid-strided LN.
template <int XPK>
__global__ __launch_bounds__(256, 2) void edge_ln_kernel(
    const float* __restrict__ x, const uint32_t* __restrict__ xpk,
    const int* __restrict__ eidx, const float* __restrict__ attr,
    const uint16_t* __restrict__ w2frag, float* __restrict__ out, int E,
    const float* __restrict__ gamma, const float* __restrict__ beta, int N) {
  __shared__ uint32_t xp_lds[64][36];   // packed f16 pairs, 32 used + pad
  __shared__ uint32_t a_pk[64][20];     // (a,a) packed f16; 17 used + pad
  __shared__ int      dst_lds[64];
  __shared__ float    red[4][32][68];   // f32 partials

  int tid = threadIdx.x;
  int w = tid >> 6, l = tid & 63, l16 = l & 15, lq = l >> 4;
  int row = tid >> 2, q = tid & 3;
  const int* srcp = eidx;
  const int* dstp = eidx + E;
  const float4* x4 = (const float4*)x;
  const float4* a4 = (const float4*)attr;
  int T = (E + 63) >> 6;
  const half8* bp = (const half8*)w2frag;

  half8 Breg[4][2][4];
#pragma unroll
  for (int si = 0; si < 4; ++si) {
    int s = 4 * si + w;
#pragma unroll
    for (int t = 0; t < 2; ++t)
#pragma unroll
      for (int c = 0; c < 4; ++c)
        Breg[si][t][c] = bp[((s * 2 + t) * 4 + c) * 64 + l];
  }
  int tx = w - 2;  // waves 2,3 take K-halves of bias slot 16
  half8 Bx[4];
  if (tx >= 0) {
#pragma unroll
    for (int c = 0; c < 4; ++c) Bx[c] = bp[((32 + tx) * 4 + c) * 64 + l];
  }

  // ---- stage first tile ----
  int tl = blockIdx.x;
  if (tl < T) {
    int cnt0 = min(64, E - tl * 64);
    bool ok = row < cnt0;
    int sidx = ok ? srcp[tl * 64 + row] : 0;
    uint4 u0 = make_uint4(0, 0, 0, 0), u1 = make_uint4(0, 0, 0, 0);
    if (XPK) {
      if (ok) {
        u0 = *(const uint4*)(xpk + sidx * 32 + q * 8);
        u1 = *(const uint4*)(xpk + sidx * 32 + q * 8 + 4);
      }
    } else if (ok) {
      float4 v0 = x4[sidx * 16 + q * 4 + 0], v1 = x4[sidx * 16 + q * 4 + 1];
      float4 v2 = x4[sidx * 16 + q * 4 + 2], v3 = x4[sidx * 16 + q * 4 + 3];
      u0 = make_uint4(pk_f16(v0.x, v0.y), pk_f16(v0.z, v0.w),
                      pk_f16(v1.x, v1.y), pk_f16(v1.z, v1.w));
      u1 = make_uint4(pk_f16(v2.x, v2.y), pk_f16(v2.z, v2.w),
                      pk_f16(v3.x, v3.y), pk_f16(v3.z, v3.w));
    }
    *(uint4*)&xp_lds[row][q * 8] = u0;
    *(uint4*)&xp_lds[row][q * 8 + 4] = u1;
    float4 av = make_float4(0.f, 0.f, 0.f, 0.f);
    if (ok) av = a4[(tl * 64 + row) * 4 + q];
    a_pk[row][q * 4 + 0] = pk_f16(av.x, av.x);
    a_pk[row][q * 4 + 1] = pk_f16(av.y, av.y);
    a_pk[row][q * 4 + 2] = pk_f16(av.z, av.z);
    a_pk[row][q * 4 + 3] = pk_f16(av.w, av.w);
    if (tid < 64) dst_lds[tid] = (tid < cnt0) ? dstp[tl * 64 + tid] : 0;
  }
  __syncthreads();

  for (; tl < T; tl += gridDim.x) {
    int cnt = min(64, E - tl * 64);
    int nxt = tl + (int)gridDim.x;
    bool havenxt = nxt < T;
    float4 xr[4];
    uint4 xu0 = make_uint4(0, 0, 0, 0), xu1 = make_uint4(0, 0, 0, 0);
    float4 ar = make_float4(0.f, 0.f, 0.f, 0.f);
    int dv = 0;
    if (havenxt) {
      int cntn = min(64, E - nxt * 64);
      bool ok = row < cntn;
      int sidx = ok ? srcp[nxt * 64 + row] : 0;
      if (XPK) {
        if (ok) {
          xu0 = *(const uint4*)(xpk + sidx * 32 + q * 8);
          xu1 = *(const uint4*)(xpk + sidx * 32 + q * 8 + 4);
        }
      } else {
#pragma unroll
        for (int j = 0; j < 4; ++j) {
          xr[j] = make_float4(0.f, 0.f, 0.f, 0.f);
          if (ok) xr[j] = x4[sidx * 16 + q * 4 + j];
        }
      }
      if (ok) ar = a4[(nxt * 64 + row) * 4 + q];
      if (ok) dv = dstp[nxt * 64 + row];
    }

#pragma unroll
    for (int p = 0; p < 2; ++p) {
      floatx4 acc[2][4];
#pragma unroll
      for (int rt = 0; rt < 2; ++rt)
#pragma unroll
        for (int c = 0; c < 4; ++c) acc[rt][c] = (floatx4){0.f, 0.f, 0.f, 0.f};

#pragma unroll
      for (int rt = 0; rt < 2; ++rt) {
        int arow = p * 32 + rt * 16 + l16;
        uint4 xp0 = *(const uint4*)&xp_lds[arow][lq * 4];        // kstep 0
        uint4 xp1 = *(const uint4*)&xp_lds[arow][16 + lq * 4];   // kstep 1
#pragma unroll
        for (int si = 0; si < 4; ++si) {
          uint32_t apk = a_pk[arow][4 * si + w];
          HFrag A0, A1;
          A0.u[0] = pk_mul_f16(xp0.x, apk);
          A0.u[1] = pk_mul_f16(xp0.y, apk);
          A0.u[2] = pk_mul_f16(xp0.z, apk);
          A0.u[3] = pk_mul_f16(xp0.w, apk);
          A1.u[0] = pk_mul_f16(xp1.x, apk);
          A1.u[1] = pk_mul_f16(xp1.y, apk);
          A1.u[2] = pk_mul_f16(xp1.z, apk);
          A1.u[3] = pk_mul_f16(xp1.w, apk);
#pragma unroll
          for (int c = 0; c < 4; ++c) {
            acc[rt][c] = __builtin_amdgcn_mfma_f32_16x16x32_f16(
                A0.h8, Breg[si][0][c], acc[rt][c], 0, 0, 0);
            acc[rt][c] = __builtin_amdgcn_mfma_f32_16x16x32_f16(
                A1.h8, Breg[si][1][c], acc[rt][c], 0, 0, 0);
          }
        }
        if (tx >= 0) {  // bias slot, a == 1: A = raw x-frag (free)
          HFrag Ax;
          Ax.u4 = (tx == 0) ? xp0 : xp1;
#pragma unroll
          for (int c = 0; c < 4; ++c)
            acc[rt][c] = __builtin_amdgcn_mfma_f32_16x16x32_f16(
                Ax.h8, Bx[c], acc[rt][c], 0, 0, 0);
        }
      }

#pragma unroll
      for (int rt = 0; rt < 2; ++rt)
#pragma unroll
        for (int c = 0; c < 4; ++c) {
          int f = c * 16 + l16;
#pragma unroll
          for (int r = 0; r < 4; ++r)
            red[w][rt * 16 + lq * 4 + r][f] = acc[rt][c][r];
        }
      __syncthreads();

#pragma unroll
      for (int c = 0; c < 4; ++c) {
        int f = c * 16 + l16;
#pragma unroll
        for (int r = 0; r < 2; ++r) {
          int rr = w * 8 + lq * 2 + r;
          float s = red[0][rr][f] + red[1][rr][f] + red[2][rr][f] + red[3][rr][f];
          int grow = p * 32 + rr;
          if (grow < cnt) atomicAdd(&out[dst_lds[grow] * 64 + f], s);
        }
      }
      __syncthreads();
    }

    if (havenxt) {
      if (XPK) {
        *(uint4*)&xp_lds[row][q * 8] = xu0;
        *(uint4*)&xp_lds[row][q * 8 + 4] = xu1;
      } else {
        uint4 u0 = make_uint4(pk_f16(xr[0].x, xr[0].y), pk_f16(xr[0].z, xr[0].w),
                              pk_f16(xr[1].x, xr[1].y), pk_f16(xr[1].z, xr[1].w));
        uint4 u1 = make_uint4(pk_f16(xr[2].x, xr[2].y), pk_f16(xr[2].z, xr[2].w),
                              pk_f16(xr[3].x, xr[3].y), pk_f16(xr[3].z, xr[3].w));
        *(uint4*)&xp_lds[row][q * 8] = u0;
        *(uint4*)&xp_lds[row][q * 8 + 4] = u1;
      }
      a_pk[row][q * 4 + 0] = pk_f16(ar.x, ar.x);
      a_pk[row][q * 4 + 1] = pk_f16(ar.y, ar.y);
      a_pk[row][q * 4 + 2] = pk_f16(ar.z, ar.z);
      a_pk[row][q * 4 + 3] = pk_f16(ar.w, ar.w);
      if (q == 0) dst_lds[row] = dv;
    }
    __syncthreads();
  }

  // ---- grid-wide barrier: all atomics done & visible ----
  cg::this_grid().sync();

  // ---- LN phase: grid-strided rows, one wave per row ----
  float gm = gamma[l], bt = beta[l];
  for (int r = blockIdx.x * 4 + w; r < N; r += gridDim.x * 4) {
    float v = out[r * 64 + l];
    float s = v;
#pragma unroll
    for (int m = 32; m >= 1; m >>= 1) s += __shfl_xor(s, m);
    float mu = s * 0.015625f;
    float d = v - mu;
    float qv = d * d;
#pragma unroll
    for (int m = 32; m >= 1; m >>= 1) qv += __shfl_xor(qv, m);
    float var = qv * 0.015625f;
    out[r * 64 + l] = d * rsqrtf(var + 1e-5f) * gm + bt;
  }
}

extern "C" void kernel_launch(void* const* d_in, const int* in_sizes, int n_in,
                              void* d_out, int out_size, void* d_ws, size_t ws_size,
                              hipStream_t stream) {
  const float* x      = (const float*)d_in[0];
  const int*   eidx   = (const int*)d_in[1];
  const float* attr   = (const float*)d_in[2];
  const float* W_edge = (const float*)d_in[3];
  const float* b_edge = (const float*)d_in[4];
  const float* W_root = (const float*)d_in[5];
  const float* bias   = (const float*)d_in[6];
  const float* W_res  = (const float*)d_in[7];
  const float* b_res  = (const float*)d_in[8];
  const float* gamma  = (const float*)d_in[9];
  const float* beta   = (const float*)d_in[10];
  int N = in_sizes[0] / 64;
  int E = in_sizes[1] / 2;
  float* out = (float*)d_out;
  uint16_t* w2frag = (uint16_t*)((char*)d_ws + W2FRAG_OFF);

  size_t need = (size_t)XBF_OFF + (size_t)N * 128;
  bool usepk = ws_size >= need;
  uint32_t* xpk = usepk ? (uint32_t*)((char*)d_ws + XBF_OFF) : nullptr;

  int nBase = (N + 63) / 64;
  k1_kernel<<<PREP_BLOCKS + nBase, 256, 0, stream>>>(
      x, W_edge, b_edge, W_root, bias, W_res, b_res, w2frag, out, xpk, N);

  int T = (E + 63) / 64;
  // clamp grid to co-residency (deadlock guard)
  int maxB = 0;
  if (usepk)
    (void)hipOccupancyMaxActiveBlocksPerMultiprocessor(&maxB, edge_ln_kernel<1>, 256, 0);
  else
    (void)hipOccupancyMaxActiveBlocksPerMultiprocessor(&maxB, edge_ln_kernel<0>, 256, 0);
  if (maxB < 1) maxB = 1;
  int G = maxB * 256;
  if (G > 512) G = 512;
  if (G > T) G = T;

  void* kargs[] = {(void*)&x, (void*)&xpk, (void*)&eidx, (void*)&attr,
                   (void*)&w2frag, (void*)&out, (void*)&E,
                   (void*)&gamma, (void*)&beta, (void*)&N};
  if (usepk)
    (void)hipLaunchCooperativeKernel((void*)edge_ln_kernel<1>, dim3(G), dim3(256),
                                     kargs, 0, stream);
  else
    (void)hipLaunchCooperativeKernel((void*)edge_ln_kernel<0>, dim3(G), dim3(256),
                                     kargs, 0, stream);
}

// Round 25
// 73.022 us; speedup vs baseline: 1.8095x; 1.8095x over previous
//
#include <hip/hip_runtime.h>
#include <stdint.h>

// ============================================================================
// LaneGraphConvLayerShared: NNConv(edge-conditioned) + root + residual + LN
//
// msg[e,f] = (A_e @ W2)[f], A_e[k*64+d]=a[e,k]*x[src,d]; slot16: a=1, b_edge
//
// R24 post-mortem: cooperative edge+ln fusion regressed 73.5->132us (occupancy
//   query clamped G to 256; grid.sync tail). REVERT to R23 = FINAL.
// R23 (73.5us): k1(prep+base+xpk emit) -> edge -> ln.
//   Edge: 64-edge tiles, slot-split across 4 waves, f16 packed x/a in LDS,
//   A-frags via v_pk_mul_f16 (a-scale folded into A), f16 MFMA, f32 LDS
//   cross-wave reduce, line-coalesced atomic scatter, deferred-stage
//   prefetch, G=512 (2 blocks/CU, register-capped occupancy).
// Session ledger: scatter-coalescing essential (R3: 300MB writeback without);
//   dst-sort null (R8); decoupling null (R11); bf16/f16 gather+pipeline wins
//   (R12,R20); >128-reg structures spill (R5,R13,R14); B-in-LDS kills
//   occupancy (R6); traffic-cut code-motion loses to pipelining (R21).
// ============================================================================

typedef _Float16 half8 __attribute__((ext_vector_type(8)));
typedef float floatx4 __attribute__((ext_vector_type(4)));

union HFrag { half8 h8; uint32_t u[4]; uint4 u4; };

__device__ __forceinline__ uint32_t pk_f16(float lo, float hi) {
  auto h = __builtin_amdgcn_cvt_pkrtz(lo, hi);   // __fp16 ext_vector(2)
  union { decltype(h) h2; uint32_t u; } cv;
  cv.h2 = h;
  return cv.u;
}

__device__ __forceinline__ uint32_t pk_mul_f16(uint32_t a, uint32_t b) {
  uint32_t r;
  asm("v_pk_mul_f16 %0, %1, %2" : "=v"(r) : "v"(a), "v"(b));
  return r;
}

__device__ __forceinline__ uint32_t cvt_pk_bf16(float lo, float hi) {
  uint32_t r;
  asm("v_cvt_pk_bf16_f32 %0, %1, %2" : "=v"(r) : "v"(lo), "v"(hi));
  return r;
}

__device__ __forceinline__ uint16_t f32_to_bf16_bits(float x) {
  uint32_t u = __float_as_uint(x);
  u += 0x7fffu + ((u >> 16) & 1u);
  return (uint16_t)(u >> 16);
}

// ws layout:
//   [0,       139264): W2frag  f16 [slot17][kstep2][c4][lane64][i8]
//   [148480, +N*128 ): x_f16 packed pairs [N][32 u32]  (if ws_size permits)
#define W2FRAG_OFF 0
#define XBF_OFF    148480
#define PREP_ELEMS 69632
#define PREP_BLOCKS 272  // ceil(69632/256)

// k1: blocks [0,PREP_BLOCKS) build w2frag (f16 B-frags incl bias slot);
//     blocks [PREP_BLOCKS, +nBase) do base GEMM + emit packed-f16 x.
__global__ __launch_bounds__(256) void k1_kernel(
    const float* __restrict__ x,
    const float* __restrict__ W_edge, const float* __restrict__ b_edge,
    const float* __restrict__ W_root, const float* __restrict__ bias,
    const float* __restrict__ W_res,  const float* __restrict__ b_res,
    uint16_t* __restrict__ w2frag, float* __restrict__ out,
    uint32_t* __restrict__ xpk, int N) {
  int tid = threadIdx.x;
  if (blockIdx.x < PREP_BLOCKS) {
    int gid = blockIdx.x * 256 + tid;
    if (gid < PREP_ELEMS) {
      int i = gid & 7, l = (gid >> 3) & 63, c = (gid >> 9) & 3;
      int t = (gid >> 11) & 1, s = gid >> 12;
      int d = t * 32 + 8 * (l >> 4) + i;
      int f = c * 16 + (l & 15);
      float v = (s < 16) ? W_edge[s * 4096 + d * 64 + f] : b_edge[d * 64 + f];
      w2frag[gid] = (uint16_t)(pk_f16(v, 0.f) & 0xffffu);   // f16 bits
    }
    return;
  }
  typedef short short8 __attribute__((ext_vector_type(8)));
  union AFrag { short8 s8; uint32_t u[4]; };
  int bb = blockIdx.x - PREP_BLOCKS;
  int w = tid >> 6, l = tid & 63;
  int l16 = l & 15, lq = l >> 4;
  // Wsum B-frags built inline (W_root/W_res are 16KB L2-hot arrays)
  union BF { short8 s8; uint16_t h[8]; } Bf[2][4];
#pragma unroll
  for (int t = 0; t < 2; ++t)
#pragma unroll
    for (int c = 0; c < 4; ++c)
#pragma unroll
      for (int i = 0; i < 8; ++i) {
        int d = t * 32 + 8 * lq + i;
        int f = c * 16 + l16;
        Bf[t][c].h[i] = f32_to_bf16_bits(W_root[d * 64 + f] + W_res[d * 64 + f]);
      }
  int arow = bb * 64 + w * 16 + l16;
  float xv[16];
#pragma unroll
  for (int t = 0; t < 2; ++t)
#pragma unroll
    for (int i = 0; i < 8; ++i)
      xv[t * 8 + i] = (arow < N) ? x[arow * 64 + t * 32 + 8 * lq + i] : 0.0f;
  if (xpk != nullptr && arow < N) {
#pragma unroll
    for (int t = 0; t < 2; ++t) {
      uint4 c;
      c.x = pk_f16(xv[t * 8 + 0], xv[t * 8 + 1]);
      c.y = pk_f16(xv[t * 8 + 2], xv[t * 8 + 3]);
      c.z = pk_f16(xv[t * 8 + 4], xv[t * 8 + 5]);
      c.w = pk_f16(xv[t * 8 + 6], xv[t * 8 + 7]);
      *(uint4*)(xpk + arow * 32 + t * 16 + lq * 4) = c;
    }
  }
  AFrag A[2];
#pragma unroll
  for (int t = 0; t < 2; ++t)
#pragma unroll
    for (int j = 0; j < 4; ++j)
      A[t].u[j] = cvt_pk_bf16(xv[t * 8 + 2 * j], xv[t * 8 + 2 * j + 1]);
  floatx4 acc[4];
#pragma unroll
  for (int c = 0; c < 4; ++c) acc[c] = (floatx4){0.f, 0.f, 0.f, 0.f};
#pragma unroll
  for (int t = 0; t < 2; ++t)
#pragma unroll
    for (int c = 0; c < 4; ++c)
      acc[c] = __builtin_amdgcn_mfma_f32_16x16x32_bf16(A[t].s8, Bf[t][c].s8, acc[c], 0, 0, 0);
#pragma unroll
  for (int c = 0; c < 4; ++c) {
    int f = c * 16 + l16;
    float bs = bias[f] + b_res[f];
#pragma unroll
    for (int r = 0; r < 4; ++r) {
      int row = bb * 64 + w * 16 + lq * 4 + r;
      if (row < N) out[row * 64 + f] = acc[c][r] + bs;
    }
  }
}

// edge: f16 packed x/a, pk_mul A-build, f16 MFMA, f32 red, coalesced atomics.
template <int XPK>
__global__ __launch_bounds__(256, 2) void edge_kernel(
    const float* __restrict__ x, const uint32_t* __restrict__ xpk,
    const int* __restrict__ eidx, const float* __restrict__ attr,
    const uint16_t* __restrict__ w2frag, float* __restrict__ out, int E) {
  __shared__ uint32_t xp_lds[64][36];   // packed f16 pairs, 32 used + pad
  __shared__ uint32_t a_pk[64][20];     // (a,a) packed f16; 17 used + pad
  __shared__ int      dst_lds[64];
  __shared__ float    red[4][32][68];   // f32 partials

  int tid = threadIdx.x;
  int w = tid >> 6, l = tid & 63, l16 = l & 15, lq = l >> 4;
  int row = tid >> 2, q = tid & 3;
  const int* srcp = eidx;
  const int* dstp = eidx + E;
  const float4* x4 = (const float4*)x;
  const float4* a4 = (const float4*)attr;
  int T = (E + 63) >> 6;
  const half8* bp = (const half8*)w2frag;

  half8 Breg[4][2][4];
#pragma unroll
  for (int si = 0; si < 4; ++si) {
    int s = 4 * si + w;
#pragma unroll
    for (int t = 0; t < 2; ++t)
#pragma unroll
      for (int c = 0; c < 4; ++c)
        Breg[si][t][c] = bp[((s * 2 + t) * 4 + c) * 64 + l];
  }
  int tx = w - 2;  // waves 2,3 take K-halves of bias slot 16
  half8 Bx[4];
  if (tx >= 0) {
#pragma unroll
    for (int c = 0; c < 4; ++c) Bx[c] = bp[((32 + tx) * 4 + c) * 64 + l];
  }

  // ---- stage first tile ----
  int tl = blockIdx.x;
  if (tl < T) {
    int cnt0 = min(64, E - tl * 64);
    bool ok = row < cnt0;
    int sidx = ok ? srcp[tl * 64 + row] : 0;
    uint4 u0 = make_uint4(0, 0, 0, 0), u1 = make_uint4(0, 0, 0, 0);
    if (XPK) {
      if (ok) {
        u0 = *(const uint4*)(xpk + sidx * 32 + q * 8);
        u1 = *(const uint4*)(xpk + sidx * 32 + q * 8 + 4);
      }
    } else if (ok) {
      float4 v0 = x4[sidx * 16 + q * 4 + 0], v1 = x4[sidx * 16 + q * 4 + 1];
      float4 v2 = x4[sidx * 16 + q * 4 + 2], v3 = x4[sidx * 16 + q * 4 + 3];
      u0 = make_uint4(pk_f16(v0.x, v0.y), pk_f16(v0.z, v0.w),
                      pk_f16(v1.x, v1.y), pk_f16(v1.z, v1.w));
      u1 = make_uint4(pk_f16(v2.x, v2.y), pk_f16(v2.z, v2.w),
                      pk_f16(v3.x, v3.y), pk_f16(v3.z, v3.w));
    }
    *(uint4*)&xp_lds[row][q * 8] = u0;
    *(uint4*)&xp_lds[row][q * 8 + 4] = u1;
    float4 av = make_float4(0.f, 0.f, 0.f, 0.f);
    if (ok) av = a4[(tl * 64 + row) * 4 + q];
    a_pk[row][q * 4 + 0] = pk_f16(av.x, av.x);
    a_pk[row][q * 4 + 1] = pk_f16(av.y, av.y);
    a_pk[row][q * 4 + 2] = pk_f16(av.z, av.z);
    a_pk[row][q * 4 + 3] = pk_f16(av.w, av.w);
    if (tid < 64) dst_lds[tid] = (tid < cnt0) ? dstp[tl * 64 + tid] : 0;
  }
  __syncthreads();

  for (; tl < T; tl += gridDim.x) {
    int cnt = min(64, E - tl * 64);
    int nxt = tl + (int)gridDim.x;
    bool havenxt = nxt < T;
    // early-issue next tile's gather; raw words held to stage-write
    float4 xr[4];
    uint4 xu0 = make_uint4(0, 0, 0, 0), xu1 = make_uint4(0, 0, 0, 0);
    float4 ar = make_float4(0.f, 0.f, 0.f, 0.f);
    int dv = 0;
    if (havenxt) {
      int cntn = min(64, E - nxt * 64);
      bool ok = row < cntn;
      int sidx = ok ? srcp[nxt * 64 + row] : 0;
      if (XPK) {
        if (ok) {
          xu0 = *(const uint4*)(xpk + sidx * 32 + q * 8);
          xu1 = *(const uint4*)(xpk + sidx * 32 + q * 8 + 4);
        }
      } else {
#pragma unroll
        for (int j = 0; j < 4; ++j) {
          xr[j] = make_float4(0.f, 0.f, 0.f, 0.f);
          if (ok) xr[j] = x4[sidx * 16 + q * 4 + j];
        }
      }
      if (ok) ar = a4[(nxt * 64 + row) * 4 + q];
      if (ok) dv = dstp[nxt * 64 + row];
    }

#pragma unroll
    for (int p = 0; p < 2; ++p) {
      floatx4 acc[2][4];
#pragma unroll
      for (int rt = 0; rt < 2; ++rt)
#pragma unroll
        for (int c = 0; c < 4; ++c) acc[rt][c] = (floatx4){0.f, 0.f, 0.f, 0.f};

#pragma unroll
      for (int rt = 0; rt < 2; ++rt) {
        int arow = p * 32 + rt * 16 + l16;
        uint4 xp0 = *(const uint4*)&xp_lds[arow][lq * 4];        // kstep 0
        uint4 xp1 = *(const uint4*)&xp_lds[arow][16 + lq * 4];   // kstep 1
#pragma unroll
        for (int si = 0; si < 4; ++si) {
          uint32_t apk = a_pk[arow][4 * si + w];
          HFrag A0, A1;
          A0.u[0] = pk_mul_f16(xp0.x, apk);
          A0.u[1] = pk_mul_f16(xp0.y, apk);
          A0.u[2] = pk_mul_f16(xp0.z, apk);
          A0.u[3] = pk_mul_f16(xp0.w, apk);
          A1.u[0] = pk_mul_f16(xp1.x, apk);
          A1.u[1] = pk_mul_f16(xp1.y, apk);
          A1.u[2] = pk_mul_f16(xp1.z, apk);
          A1.u[3] = pk_mul_f16(xp1.w, apk);
#pragma unroll
          for (int c = 0; c < 4; ++c) {
            acc[rt][c] = __builtin_amdgcn_mfma_f32_16x16x32_f16(
                A0.h8, Breg[si][0][c], acc[rt][c], 0, 0, 0);
            acc[rt][c] = __builtin_amdgcn_mfma_f32_16x16x32_f16(
                A1.h8, Breg[si][1][c], acc[rt][c], 0, 0, 0);
          }
        }
        if (tx >= 0) {  // bias slot, a == 1: A = raw x-frag (free)
          HFrag Ax;
          Ax.u4 = (tx == 0) ? xp0 : xp1;
#pragma unroll
          for (int c = 0; c < 4; ++c)
            acc[rt][c] = __builtin_amdgcn_mfma_f32_16x16x32_f16(
                Ax.h8, Bx[c], acc[rt][c], 0, 0, 0);
        }
      }

      // partial -> LDS (f32)
#pragma unroll
      for (int rt = 0; rt < 2; ++rt)
#pragma unroll
        for (int c = 0; c < 4; ++c) {
          int f = c * 16 + l16;
#pragma unroll
          for (int r = 0; r < 4; ++r)
            red[w][rt * 16 + lq * 4 + r][f] = acc[rt][c][r];
        }
      __syncthreads();

      // cross-wave reduce + LINE-COALESCED atomic scatter (R4-verified)
#pragma unroll
      for (int c = 0; c < 4; ++c) {
        int f = c * 16 + l16;
#pragma unroll
        for (int r = 0; r < 2; ++r) {
          int rr = w * 8 + lq * 2 + r;
          float s = red[0][rr][f] + red[1][rr][f] + red[2][rr][f] + red[3][rr][f];
          int grow = p * 32 + rr;
          if (grow < cnt) atomicAdd(&out[dst_lds[grow] * 64 + f], s);
        }
      }
      __syncthreads();
    }

    // stage next tile (all reads of current tile complete)
    if (havenxt) {
      if (XPK) {
        *(uint4*)&xp_lds[row][q * 8] = xu0;
        *(uint4*)&xp_lds[row][q * 8 + 4] = xu1;
      } else {
        uint4 u0 = make_uint4(pk_f16(xr[0].x, xr[0].y), pk_f16(xr[0].z, xr[0].w),
                              pk_f16(xr[1].x, xr[1].y), pk_f16(xr[1].z, xr[1].w));
        uint4 u1 = make_uint4(pk_f16(xr[2].x, xr[2].y), pk_f16(xr[2].z, xr[2].w),
                              pk_f16(xr[3].x, xr[3].y), pk_f16(xr[3].z, xr[3].w));
        *(uint4*)&xp_lds[row][q * 8] = u0;
        *(uint4*)&xp_lds[row][q * 8 + 4] = u1;
      }
      a_pk[row][q * 4 + 0] = pk_f16(ar.x, ar.x);
      a_pk[row][q * 4 + 1] = pk_f16(ar.y, ar.y);
      a_pk[row][q * 4 + 2] = pk_f16(ar.z, ar.z);
      a_pk[row][q * 4 + 3] = pk_f16(ar.w, ar.w);
      if (q == 0) dst_lds[row] = dv;
    }
    __syncthreads();
  }
}

__global__ __launch_bounds__(256) void ln_kernel(
    float* __restrict__ out, const float* __restrict__ gamma,
    const float* __restrict__ beta, int N) {
  int w = threadIdx.x >> 6, l = threadIdx.x & 63;
  int row = blockIdx.x * 4 + w;
  if (row >= N) return;
  float v = out[row * 64 + l];
  float s = v;
#pragma unroll
  for (int m = 32; m >= 1; m >>= 1) s += __shfl_xor(s, m);
  float mu = s * 0.015625f;
  float d = v - mu;
  float q = d * d;
#pragma unroll
  for (int m = 32; m >= 1; m >>= 1) q += __shfl_xor(q, m);
  float var = q * 0.015625f;
  out[row * 64 + l] = d * rsqrtf(var + 1e-5f) * gamma[l] + beta[l];
}

extern "C" void kernel_launch(void* const* d_in, const int* in_sizes, int n_in,
                              void* d_out, int out_size, void* d_ws, size_t ws_size,
                              hipStream_t stream) {
  const float* x      = (const float*)d_in[0];
  const int*   eidx   = (const int*)d_in[1];
  const float* attr   = (const float*)d_in[2];
  const float* W_edge = (const float*)d_in[3];
  const float* b_edge = (const float*)d_in[4];
  const float* W_root = (const float*)d_in[5];
  const float* bias   = (const float*)d_in[6];
  const float* W_res  = (const float*)d_in[7];
  const float* b_res  = (const float*)d_in[8];
  const float* gamma  = (const float*)d_in[9];
  const float* beta   = (const float*)d_in[10];
  int N = in_sizes[0] / 64;
  int E = in_sizes[1] / 2;
  float* out = (float*)d_out;
  uint16_t* w2frag = (uint16_t*)((char*)d_ws + W2FRAG_OFF);

  size_t need = (size_t)XBF_OFF + (size_t)N * 128;
  bool usepk = ws_size >= need;
  uint32_t* xpk = usepk ? (uint32_t*)((char*)d_ws + XBF_OFF) : nullptr;

  int nBase = (N + 63) / 64;
  k1_kernel<<<PREP_BLOCKS + nBase, 256, 0, stream>>>(
      x, W_edge, b_edge, W_root, bias, W_res, b_res, w2frag, out, xpk, N);
  int T = (E + 63) / 64;
  int G = T < 512 ? T : 512;
  if (usepk)
    edge_kernel<1><<<G, 256, 0, stream>>>(x, xpk, eidx, attr, w2frag, out, E);
  else
    edge_kernel<0><<<G, 256, 0, stream>>>(x, xpk, eidx, attr, w2frag, out, E);
  ln_kernel<<<(N + 3) / 4, 256, 0, stream>>>(out, gamma, beta, N);
}